// Round 1
// baseline (22458.243 us; speedup 1.0000x reference)
//
#include <hip/hip_runtime.h>
#include <math.h>

#define TSTEPS 16384
#define NTAGS  1024
#define NWG    256      // one workgroup per CU
#define TPB    64       // ONE wave per WG (was 2): halves the MALL poller count
#define START_I 1022
#define STOP_I  1023

// CRF forward in the linear (exp) domain, latency-optimized.
//   p_{t+1} = e_t . (M p_t) / max(p_t),  S += log(max(p_t))
//   alpha   = S + log( sum_i p_T[i] * exp(trans[STOP,i]) )
// No LDS, no barriers: each WAVE polls the full 1024-float vector itself
// (16 values/lane, 8x u64 agent-scope loads, each instruction 512B
// contiguous across lanes). Validation is embedded in the data: stored
// value = sign(t) * (p + 1), sign flips every ring wrap (depth-2 ring),
// so 0xAA poison (-1.2e-13) and stale opposite-sign values never validate.
// Sign/offset are folded out of the hot path algebraically:
//   sum_c M[r][c]*(sg*v[c]-1) = sg * (sum M v) - (sum M)   (msum precomp)
//
// R1 vs baseline: 256 WGs x 1 wave x 4 rows/wave (was 256 x 2 x 2).
// Theory: step time is bound by the agent-scope broadcast round trip,
// inflated by poll-read contention at the coherence point (512 pollers x
// 4KB/sweep). Halving pollers halves that traffic; the extra 32 FMA/lane
// is ~60ns. Stores become one 16B-contiguous transaction per WG (lanes
// 0/16/32/48 -> 4 consecutive tags) instead of two scattered 4B stores.

__device__ __forceinline__ float min16(const float v[16]) {
    float a = fminf(v[0],  v[1]),  b = fminf(v[2],  v[3]);
    float c = fminf(v[4],  v[5]),  d = fminf(v[6],  v[7]);
    float e = fminf(v[8],  v[9]),  f = fminf(v[10], v[11]);
    float g = fminf(v[12], v[13]), h = fminf(v[14], v[15]);
    a = fminf(a, b); c = fminf(c, d); e = fminf(e, f); g = fminf(g, h);
    return fminf(fminf(a, c), fminf(e, g));
}
__device__ __forceinline__ float max16(const float v[16]) {
    float a = fmaxf(v[0],  v[1]),  b = fmaxf(v[2],  v[3]);
    float c = fmaxf(v[4],  v[5]),  d = fmaxf(v[6],  v[7]);
    float e = fmaxf(v[8],  v[9]),  f = fmaxf(v[10], v[11]);
    float g = fmaxf(v[12], v[13]), h = fmaxf(v[14], v[15]);
    a = fmaxf(a, b); c = fmaxf(c, d); e = fmaxf(e, f); g = fmaxf(g, h);
    return fmaxf(fmaxf(a, c), fmaxf(e, g));
}

__global__ __launch_bounds__(TPB)
void crf_forward_kernel(const float* __restrict__ decoded,
                        const float* __restrict__ trans,
                        float* __restrict__ out,
                        float* __restrict__ ring)
{
    const int lane = threadIdx.x;       // single wave per WG
    const int wg   = blockIdx.x;
    const int r0   = wg * 4;            // this wave's four output tags

    // ---- init: M fragments for 4 rows (cols 128k + 2*lane + h), row sums ----
    float M0[16], M1[16], M2[16], M3[16];
    float sm0 = 0.0f, sm1 = 0.0f, sm2 = 0.0f, sm3 = 0.0f;
    #pragma unroll
    for (int k = 0; k < 8; ++k) {
        const int c = 128 * k + 2 * lane;
        M0[2*k]   = __expf(trans[(size_t)(r0+0) * NTAGS + c]);
        M0[2*k+1] = __expf(trans[(size_t)(r0+0) * NTAGS + c + 1]);
        M1[2*k]   = __expf(trans[(size_t)(r0+1) * NTAGS + c]);
        M1[2*k+1] = __expf(trans[(size_t)(r0+1) * NTAGS + c + 1]);
        M2[2*k]   = __expf(trans[(size_t)(r0+2) * NTAGS + c]);
        M2[2*k+1] = __expf(trans[(size_t)(r0+2) * NTAGS + c + 1]);
        M3[2*k]   = __expf(trans[(size_t)(r0+3) * NTAGS + c]);
        M3[2*k+1] = __expf(trans[(size_t)(r0+3) * NTAGS + c + 1]);
        sm0 += M0[2*k] + M0[2*k+1];
        sm1 += M1[2*k] + M1[2*k+1];
        sm2 += M2[2*k] + M2[2*k+1];
        sm3 += M3[2*k] + M3[2*k+1];
    }
    // reduce M row sums with the SAME lane->row mapping as the step reduce:
    // final row index = lane>>4 (16-lane groups hold rows r0..r0+3)
    sm0 += __shfl_xor(sm0, 32, 64);
    sm1 += __shfl_xor(sm1, 32, 64);
    sm2 += __shfl_xor(sm2, 32, 64);
    sm3 += __shfl_xor(sm3, 32, 64);
    float gg = (lane & 32) ? sm2 : sm0;
    float hh = (lane & 32) ? sm3 : sm1;
    gg += __shfl_xor(gg, 16, 64);
    hh += __shfl_xor(hh, 16, 64);
    float msum = (lane & 16) ? hh : gg;
    msum += __shfl_xor(msum, 8, 64);
    msum += __shfl_xor(msum, 4, 64);
    msum += __shfl_xor(msum, 2, 64);
    msum += __shfl_xor(msum, 1, 64);
    // lane group g=[16g,16g+15] now holds sum(M[r0+g,:])

    const bool storer = ((lane & 15) == 0);   // lanes 0/16/32/48 -> rows r0..r0+3
    const int  myrow  = r0 + (lane >> 4);

    double s2   = 0.0;    // sum of log2(max) — maintained uniformly per wave
    float dcur  = 0.0f, dnext = 0.0f;
    if (storer) dcur = decoded[myrow];        // emission for t = 0

    for (int t = 0; t < TSTEPS; ++t) {
        const float e = __expf(dcur);         // off critical path
        if (storer && (t + 1) < TSTEPS)
            dnext = decoded[(size_t)(t + 1) * NTAGS + myrow];

        const float sg = ((t >> 1) & 1) ? -1.0f : 1.0f;

        // ---- obtain raw v (stored-form) for this lane's 16 columns ----
        float v[16];
        if (t == 0) {
            #pragma unroll
            for (int k = 0; k < 8; ++k) {
                const int c = 128 * k + 2 * lane;
                v[2*k]   = (c     == START_I) ? 2.0f : 1.0f;  // pv+1, sg=+1
                v[2*k+1] = (c + 1 == START_I) ? 2.0f : 1.0f;
            }
        } else {
            const unsigned long long* src =
                (const unsigned long long*)(ring + (size_t)(t & 1) * NTAGS) + lane;
            if (sg > 0.0f) {
                for (;;) {
                    unsigned long long q[8];
                    #pragma unroll
                    for (int k = 0; k < 8; ++k)
                        q[k] = __hip_atomic_load(src + 64 * k, __ATOMIC_RELAXED,
                                                 __HIP_MEMORY_SCOPE_AGENT);
                    #pragma unroll
                    for (int k = 0; k < 8; ++k) {
                        v[2*k]   = __uint_as_float((unsigned)q[k]);
                        v[2*k+1] = __uint_as_float((unsigned)(q[k] >> 32));
                    }
                    if (min16(v) >= 1.0f) break;      // all 16 valid
                }
            } else {
                for (;;) {
                    unsigned long long q[8];
                    #pragma unroll
                    for (int k = 0; k < 8; ++k)
                        q[k] = __hip_atomic_load(src + 64 * k, __ATOMIC_RELAXED,
                                                 __HIP_MEMORY_SCOPE_AGENT);
                    #pragma unroll
                    for (int k = 0; k < 8; ++k) {
                        v[2*k]   = __uint_as_float((unsigned)q[k]);
                        v[2*k+1] = __uint_as_float((unsigned)(q[k] >> 32));
                    }
                    if (max16(v) <= -1.0f) break;
                }
            }
        }

        // ---- per-lane raw extreme (for the global max of pv) ----
        const float Eraw = (sg > 0.0f) ? max16(v) : min16(v);

        // ---- dot products on raw v (sign/offset folded into msum) ----
        float a0 = 0.0f, a1 = 0.0f, a2 = 0.0f, a3 = 0.0f;
        #pragma unroll
        for (int j = 0; j < 16; ++j) {
            a0 = fmaf(M0[j], v[j], a0);
            a1 = fmaf(M1[j], v[j], a1);
            a2 = fmaf(M2[j], v[j], a2);
            a3 = fmaf(M3[j], v[j], a3);
        }

        // global max of pv across the wave (exact, associative)
        float ml = fmaf(sg, Eraw, -1.0f);
        ml = fmaxf(ml, __shfl_xor(ml, 32, 64));
        ml = fmaxf(ml, __shfl_xor(ml, 16, 64));
        ml = fmaxf(ml, __shfl_xor(ml,  8, 64));
        ml = fmaxf(ml, __shfl_xor(ml,  4, 64));
        ml = fmaxf(ml, __shfl_xor(ml,  2, 64));
        ml = fmaxf(ml, __shfl_xor(ml,  1, 64));

        // row-sum butterfly: pack four rows into the four 16-lane groups
        a0 += __shfl_xor(a0, 32, 64);
        a1 += __shfl_xor(a1, 32, 64);
        a2 += __shfl_xor(a2, 32, 64);
        a3 += __shfl_xor(a3, 32, 64);
        float g = (lane & 32) ? a2 : a0;
        float h = (lane & 32) ? a3 : a1;
        g += __shfl_xor(g, 16, 64);
        h += __shfl_xor(h, 16, 64);
        float b = (lane & 16) ? h : g;
        b += __shfl_xor(b, 8, 64);
        b += __shfl_xor(b, 4, 64);
        b += __shfl_xor(b, 2, 64);
        b += __shfl_xor(b, 1, 64);
        // lane group g holds sum(M[r0+g,:] . v)

        s2 += (double)__log2f(ml);            // off critical path

        if (storer) {
            const float s    = fmaf(sg, b, -msum);            // sum M . pv
            const float outv = e * s * __builtin_amdgcn_rcpf(ml);
            const int   tn   = t + 1;
            const float sgn  = ((tn >> 1) & 1) ? -1.0f : 1.0f;
            // lanes 0/16/32/48 -> 4 consecutive tags: one 16B transaction
            __hip_atomic_store(ring + (size_t)(tn & 1) * NTAGS + myrow,
                               fmaf(sgn, outv, sgn),          // sgn*(outv+1)
                               __ATOMIC_RELAXED, __HIP_MEMORY_SCOPE_AGENT);
        }
        dcur = dnext;
    }

    // ---- epilogue: wg0 folds in trans[STOP,:] ----
    if (wg == 0) {
        // p_T lives in slot (TSTEPS&1)=0 with sign +1 ((TSTEPS>>1)&1 = 0)
        const unsigned long long* src = (const unsigned long long*)ring + lane;
        float v[16];
        for (;;) {
            unsigned long long q[8];
            #pragma unroll
            for (int k = 0; k < 8; ++k)
                q[k] = __hip_atomic_load(src + 64 * k, __ATOMIC_RELAXED,
                                         __HIP_MEMORY_SCOPE_AGENT);
            #pragma unroll
            for (int k = 0; k < 8; ++k) {
                v[2*k]   = __uint_as_float((unsigned)q[k]);
                v[2*k+1] = __uint_as_float((unsigned)(q[k] >> 32));
            }
            if (min16(v) >= 1.0f) break;
        }
        float term = 0.0f;
        #pragma unroll
        for (int k = 0; k < 8; ++k) {
            const int c = 128 * k + 2 * lane;
            term = fmaf(__expf(trans[(size_t)STOP_I * NTAGS + c]),
                        v[2*k] - 1.0f, term);
            term = fmaf(__expf(trans[(size_t)STOP_I * NTAGS + c + 1]),
                        v[2*k+1] - 1.0f, term);
        }
        term += __shfl_xor(term, 32, 64);
        term += __shfl_xor(term, 16, 64);
        term += __shfl_xor(term,  8, 64);
        term += __shfl_xor(term,  4, 64);
        term += __shfl_xor(term,  2, 64);
        term += __shfl_xor(term,  1, 64);
        if (lane == 0)
            out[0] = (float)(0.6931471805599453 * (s2 + log2((double)term)));
    }
}

extern "C" void kernel_launch(void* const* d_in, const int* in_sizes, int n_in,
                              void* d_out, int out_size, void* d_ws, size_t ws_size,
                              hipStream_t stream) {
    const float* decoded = (const float*)d_in[0];   // [16384, 1024] f32
    const float* trans   = (const float*)d_in[1];   // [1024, 1024]  f32
    float* out  = (float*)d_out;
    float* ring = (float*)d_ws;                     // 2 * 1024 floats = 8 KB

    // Ring "invalid" state independent of harness poisoning (0xAA already
    // invalid, but enforce it ourselves for replay safety).
    hipMemsetAsync(ring, 0xAA, 2 * NTAGS * sizeof(float), stream);

    hipLaunchKernelGGL(crf_forward_kernel, dim3(NWG), dim3(TPB), 0, stream,
                       decoded, trans, out, ring);
}